// Round 1
// baseline (362.208 us; speedup 1.0000x reference)
//
#include <hip/hip_runtime.h>
#include <hip/hip_bf16.h>

#define B_   16
#define LQ_  2048
#define LK_  2048
#define D_   256
#define DV_  256
#define QB   64
#define KB   64
#define NW   4

typedef __bf16 bf16x8_t __attribute__((ext_vector_type(8)));
typedef short  s16x8    __attribute__((ext_vector_type(8)));
typedef short  s16x4    __attribute__((ext_vector_type(4)));
typedef float  f32x4    __attribute__((ext_vector_type(4)));

__device__ __forceinline__ unsigned short f2bf(float f) {
  unsigned int u = __builtin_bit_cast(unsigned int, f);
  u += 0x7fffu + ((u >> 16) & 1u);   // RNE (inputs are finite normals)
  return (unsigned short)(u >> 16);
}

__device__ __forceinline__ s16x8 pack8(float4 a, float4 b) {
  s16x8 r;
  r[0] = (short)f2bf(a.x); r[1] = (short)f2bf(a.y);
  r[2] = (short)f2bf(a.z); r[3] = (short)f2bf(a.w);
  r[4] = (short)f2bf(b.x); r[5] = (short)f2bf(b.y);
  r[6] = (short)f2bf(b.z); r[7] = (short)f2bf(b.w);
  return r;
}

__global__ __launch_bounds__(256) void attn_fwd(
    const float* __restrict__ Q, const float* __restrict__ K,
    const float* __restrict__ V, const int* __restrict__ VL,
    float* __restrict__ O) {
  // K tile: [row][d ^ ((row&7)<<3)]   (swizzle kills stride-512B bank conflicts)
  __shared__ __align__(16) unsigned short lds_k[KB * D_];
  // V tile transposed: [dv][k ^ ((dv&7)<<3)]
  __shared__ __align__(16) unsigned short lds_v[DV_ * KB];
  // per-wave P scratch: [q][k ^ ((q&7)<<3)]
  __shared__ __align__(16) unsigned short lds_p[NW][16 * KB];

  const int tid  = threadIdx.x;
  const int wid  = tid >> 6;
  const int lane = tid & 63;
  const int l15  = lane & 15;
  const int lg   = lane >> 4;

  const int bid = blockIdx.x;
  const int b   = bid >> 5;   // 32 q-tiles per batch (consecutive blocks share K/V)
  const int qt  = bid & 31;

  // valid_len: robust to int32 or int64 storage (valid_len >= 1 always,
  // so vl[1]==0 iff the buffer is little-endian int64)
  int n_k = (VL[1] == 0) ? VL[2 * b] : VL[b];
  if (n_k < 1) n_k = 1;
  if (n_k > LK_) n_k = LK_;

  const int qbase = qt * QB + wid * 16;

  // ---- Q fragments: lane holds Q[qbase+l15][dk*32 + lg*8 .. +8] ----
  s16x8 qf[8];
  {
    const float* qp = Q + ((size_t)b * LQ_ + qbase + l15) * D_ + lg * 8;
    #pragma unroll
    for (int dk = 0; dk < 8; ++dk) {
      float4 a = *(const float4*)(qp + dk * 32);
      float4 c = *(const float4*)(qp + dk * 32 + 4);
      qf[dk] = pack8(a, c);
    }
  }

  f32x4 o[16];
  #pragma unroll
  for (int c = 0; c < 16; ++c) o[c] = (f32x4){0.f, 0.f, 0.f, 0.f};
  float m[4]    = {-INFINITY, -INFINITY, -INFINITY, -INFINITY};
  float lsum[4] = {0.f, 0.f, 0.f, 0.f};

  const float* kb = K + (size_t)b * LK_ * D_;
  const float* vb = V + (size_t)b * LK_ * DV_;
  const int nt = (n_k + KB - 1) / KB;

  for (int kt = 0; kt < nt; ++kt) {
    __syncthreads();   // previous tile's compute done before overwrite
    // ---- stage K tile (fp32 -> bf16, swizzled) ----
    {
      const float* src = kb + (size_t)kt * KB * D_;
      #pragma unroll
      for (int p = 0; p < 8; ++p) {
        int e = (p * 256 + tid) * 8;        // coalesced 32B/lane
        int r = e >> 8;
        int d = e & 255;
        float4 a = *(const float4*)(src + e);
        float4 c = *(const float4*)(src + e + 4);
        int off = r * 256 + (d ^ ((r & 7) << 3));
        *(s16x8*)(&lds_k[off]) = pack8(a, c);
      }
    }
    // ---- stage V tile transposed (read 4 k-rows x 8 dv, write b64 columns) ----
    {
      const float* src = vb + (size_t)kt * KB * DV_;
      #pragma unroll
      for (int p = 0; p < 2; ++p) {
        int item = p * 256 + tid;
        int k0  = (item >> 5) * 4;
        int dv0 = (item & 31) * 8;
        float va[4][8];
        #pragma unroll
        for (int r = 0; r < 4; ++r) {
          float4 x = *(const float4*)(src + (k0 + r) * DV_ + dv0);
          float4 y = *(const float4*)(src + (k0 + r) * DV_ + dv0 + 4);
          va[r][0]=x.x; va[r][1]=x.y; va[r][2]=x.z; va[r][3]=x.w;
          va[r][4]=y.x; va[r][5]=y.y; va[r][6]=y.z; va[r][7]=y.w;
        }
        #pragma unroll
        for (int i = 0; i < 8; ++i) {
          int dv = dv0 + i;
          s16x4 w;
          w[0]=(short)f2bf(va[0][i]); w[1]=(short)f2bf(va[1][i]);
          w[2]=(short)f2bf(va[2][i]); w[3]=(short)f2bf(va[3][i]);
          int off = dv * 64 + (k0 ^ ((dv & 7) << 3));
          *(s16x4*)(&lds_v[off]) = w;
        }
      }
    }
    __syncthreads();

    // ---- S = (Q K^T): 4 col-frags x 8 k-chunks ----
    f32x4 s[4];
    #pragma unroll
    for (int kc = 0; kc < 4; ++kc) {
      f32x4 acc = (f32x4){0.f, 0.f, 0.f, 0.f};
      int krow = kc * 16 + l15;
      int sw = (krow & 7) << 3;
      #pragma unroll
      for (int dk = 0; dk < 8; ++dk) {
        int off = krow * 256 + ((dk * 32 + lg * 8) ^ sw);
        s16x8 kf = *(const s16x8*)(&lds_k[off]);
        acc = __builtin_amdgcn_mfma_f32_16x16x32_bf16(
            __builtin_bit_cast(bf16x8_t, qf[dk]),
            __builtin_bit_cast(bf16x8_t, kf), acc, 0, 0, 0);
      }
      s[kc] = acc;
    }

    // ---- scale + key mask ----
    #pragma unroll
    for (int kc = 0; kc < 4; ++kc) {
      int gk = kt * KB + kc * 16 + l15;
      #pragma unroll
      for (int j = 0; j < 4; ++j) {
        float v = s[kc][j] * 0.0625f;
        s[kc][j] = (gk < n_k) ? v : -INFINITY;
      }
    }

    // ---- online softmax (rows owned per 16-lane group) ----
    float pm[4];
    #pragma unroll
    for (int j = 0; j < 4; ++j)
      pm[j] = fmaxf(fmaxf(s[0][j], s[1][j]), fmaxf(s[2][j], s[3][j]));
    #pragma unroll
    for (int off = 1; off < 16; off <<= 1) {
      #pragma unroll
      for (int j = 0; j < 4; ++j)
        pm[j] = fmaxf(pm[j], __shfl_xor(pm[j], off, 64));
    }
    float sc[4];
    #pragma unroll
    for (int j = 0; j < 4; ++j) {
      float mn = fmaxf(m[j], pm[j]);
      sc[j] = __expf(m[j] - mn);   // first tile: exp(-inf)=0
      m[j] = mn;
    }
    float psum[4] = {0.f, 0.f, 0.f, 0.f};
    #pragma unroll
    for (int kc = 0; kc < 4; ++kc) {
      #pragma unroll
      for (int j = 0; j < 4; ++j) {
        float p = __expf(s[kc][j] - m[j]);   // masked cols -> exp(-inf)=0
        psum[j] += p;
        int r = lg * 4 + j;
        int col = kc * 16 + l15;
        lds_p[wid][r * 64 + (col ^ ((r & 7) << 3))] = f2bf(p);
      }
    }
    #pragma unroll
    for (int off = 1; off < 16; off <<= 1) {
      #pragma unroll
      for (int j = 0; j < 4; ++j)
        psum[j] += __shfl_xor(psum[j], off, 64);
    }
    #pragma unroll
    for (int j = 0; j < 4; ++j) lsum[j] = lsum[j] * sc[j] + psum[j];
    #pragma unroll
    for (int c = 0; c < 16; ++c) {
      #pragma unroll
      for (int j = 0; j < 4; ++j) o[c][j] *= sc[j];
    }

    // ---- P fragments back from per-wave LDS (same wave: no barrier) ----
    s16x8 pa[2];
    #pragma unroll
    for (int kk = 0; kk < 2; ++kk) {
      int r = l15;
      int k = kk * 32 + lg * 8;
      pa[kk] = *(const s16x8*)(&lds_p[wid][r * 64 + (k ^ ((r & 7) << 3))]);
    }
    // ---- O += P V ----
    #pragma unroll
    for (int c = 0; c < 16; ++c) {
      #pragma unroll
      for (int kk = 0; kk < 2; ++kk) {
        int dv = c * 16 + l15;
        int k = kk * 32 + lg * 8;
        s16x8 vf = *(const s16x8*)(&lds_v[dv * 64 + (k ^ ((dv & 7) << 3))]);
        o[c] = __builtin_amdgcn_mfma_f32_16x16x32_bf16(
            __builtin_bit_cast(bf16x8_t, pa[kk]),
            __builtin_bit_cast(bf16x8_t, vf), o[c], 0, 0, 0);
      }
    }
  }

  // ---- epilogue: O / l ----
  float inv[4];
  #pragma unroll
  for (int j = 0; j < 4; ++j) inv[j] = 1.0f / lsum[j];
  float* ob = O + ((size_t)b * LQ_ + qbase) * DV_;
  #pragma unroll
  for (int c = 0; c < 16; ++c) {
    #pragma unroll
    for (int j = 0; j < 4; ++j) {
      int r = lg * 4 + j;
      ob[(size_t)r * DV_ + c * 16 + l15] = o[c][j] * inv[j];
    }
  }
}

extern "C" void kernel_launch(void* const* d_in, const int* in_sizes, int n_in,
                              void* d_out, int out_size, void* d_ws, size_t ws_size,
                              hipStream_t stream) {
  const float* Q  = (const float*)d_in[0];
  const float* K  = (const float*)d_in[1];
  const float* V  = (const float*)d_in[2];
  const int*   VL = (const int*)d_in[3];
  float* O = (float*)d_out;
  attn_fwd<<<dim3(B_ * (LQ_ / QB)), dim3(256), 0, stream>>>(Q, K, V, VL, O);
}

// Round 2
// 168.048 us; speedup vs baseline: 2.1554x; 2.1554x over previous
//
#include <hip/hip_runtime.h>
#include <hip/hip_bf16.h>

#define B_   16
#define LQ_  2048
#define LK_  2048
#define D_   256
#define DV_  256
#define QB   64
#define NW   4

typedef __bf16 bf16x8_t __attribute__((ext_vector_type(8)));
typedef short  s16x8    __attribute__((ext_vector_type(8)));
typedef short  s16x4    __attribute__((ext_vector_type(4)));
typedef float  f32x4    __attribute__((ext_vector_type(4)));

__device__ __forceinline__ unsigned short f2bf(float f) {
  unsigned int u = __builtin_bit_cast(unsigned int, f);
  u += 0x7fffu + ((u >> 16) & 1u);   // RNE (inputs are finite normals)
  return (unsigned short)(u >> 16);
}

__device__ __forceinline__ s16x8 pack8(float4 a, float4 b) {
  s16x8 r;
  r[0] = (short)f2bf(a.x); r[1] = (short)f2bf(a.y);
  r[2] = (short)f2bf(a.z); r[3] = (short)f2bf(a.w);
  r[4] = (short)f2bf(b.x); r[5] = (short)f2bf(b.y);
  r[6] = (short)f2bf(b.z); r[7] = (short)f2bf(b.w);
  return r;
}

__device__ __forceinline__ void glds16(const unsigned short* g, unsigned short* l) {
  __builtin_amdgcn_global_load_lds(
      (const __attribute__((address_space(1))) unsigned int*)g,
      (__attribute__((address_space(3))) unsigned int*)l, 16, 0, 0);
}

// ---------- prepass: K -> bf16, row-major, chunk-XOR pre-swizzled ----------
// wsK[gr*256 + (c^(gr&7))*8 + e] = bf16(K[gr*256 + c*8 + e])
__global__ __launch_bounds__(256) void prep_k(const float* __restrict__ K,
                                              unsigned short* __restrict__ wsK) {
  int gid = blockIdx.x * 256 + threadIdx.x;     // 1,048,576 items
  int gr = gid >> 5;
  int c  = gid & 31;
  const float* src = K + ((size_t)gr << 8) + c * 8;
  float4 a = *(const float4*)(src);
  float4 b = *(const float4*)(src + 4);
  *(s16x8*)(wsK + ((size_t)gr << 8) + ((c ^ (gr & 7)) << 3)) = pack8(a, b);
}

// ---------- prepass: V -> bf16, transposed per 32-k tile, chunk-XOR swizzled --
// tile blk (= b*64 + t2): wsV[blk*8192 + dv*32 + (cs^((dv>>1)&3))*8 + e]
//   = bf16(V[(blk*32 + cs*8 + e)*256 + dv])
__global__ __launch_bounds__(256) void prep_v(const float* __restrict__ V,
                                              unsigned short* __restrict__ wsV) {
  __shared__ unsigned short t[256 * 40];        // [dv][40] pad, rows 16B-aligned
  const int tid = threadIdx.x;
  const float* src = V + (size_t)blockIdx.x * 32 * 256;
  #pragma unroll
  for (int i = 0; i < 8; ++i) {
    int idx = i * 256 + tid;
    int k   = idx >> 6;
    int dv0 = (idx & 63) * 4;
    float4 x = *(const float4*)(src + k * 256 + dv0);
    t[(dv0 + 0) * 40 + k] = f2bf(x.x);
    t[(dv0 + 1) * 40 + k] = f2bf(x.y);
    t[(dv0 + 2) * 40 + k] = f2bf(x.z);
    t[(dv0 + 3) * 40 + k] = f2bf(x.w);
  }
  __syncthreads();
  unsigned short* dst = wsV + (size_t)blockIdx.x * 8192;
  #pragma unroll
  for (int i = 0; i < 4; ++i) {
    int idx = i * 256 + tid;
    int dv = idx >> 2;
    int cs = idx & 3;
    int c2 = cs ^ ((dv >> 1) & 3);
    s16x8 v = *(const s16x8*)(&t[dv * 40 + cs * 8]);
    *(s16x8*)(dst + dv * 32 + c2 * 8) = v;
  }
}

// ---------- main v2: bf16 tiles via global_load_lds, KB=32 double-buffered ----
__global__ __launch_bounds__(256) void attn_fwd2(
    const float* __restrict__ Q, const unsigned short* __restrict__ wsK,
    const unsigned short* __restrict__ wsV, const int* __restrict__ VL,
    float* __restrict__ O) {
  __shared__ __align__(16) unsigned short lds_k[2][32 * 256];  // 16KB each
  __shared__ __align__(16) unsigned short lds_v[2][256 * 32];  // 16KB each
  __shared__ __align__(16) unsigned short lds_p[NW][16 * 32];  // 1KB/wave

  const int tid  = threadIdx.x;
  const int wid  = tid >> 6;
  const int lane = tid & 63;
  const int l15  = lane & 15;
  const int lg   = lane >> 4;

  const int bid = blockIdx.x;
  const int b   = bid >> 5;
  const int qt  = bid & 31;

  int n_k = (VL[1] == 0) ? VL[2 * b] : VL[b];
  if (n_k < 1) n_k = 1;
  if (n_k > LK_) n_k = LK_;
  const int nt = (n_k + 31) >> 5;

  const int qbase = qt * QB + wid * 16;

  // Q fragments: lane holds Q[qbase+l15][dk*32 + lg*8 .. +8]
  s16x8 qf[8];
  {
    const float* qp = Q + ((size_t)b * LQ_ + qbase + l15) * D_ + lg * 8;
    #pragma unroll
    for (int dk = 0; dk < 8; ++dk) {
      float4 a = *(const float4*)(qp + dk * 32);
      float4 c = *(const float4*)(qp + dk * 32 + 4);
      qf[dk] = pack8(a, c);
    }
  }

  f32x4 o[16];
  #pragma unroll
  for (int c = 0; c < 16; ++c) o[c] = (f32x4){0.f, 0.f, 0.f, 0.f};
  float m[4]    = {-INFINITY, -INFINITY, -INFINITY, -INFINITY};
  float lsum[4] = {0.f, 0.f, 0.f, 0.f};

  const unsigned short* kb  = wsK + (size_t)b * LK_ * D_;
  const unsigned short* vbw = wsV + (size_t)b * 64 * 8192;

  // prologue: stage tile 0 into buf 0
  {
    const unsigned short* ks = kb;
    const unsigned short* vs = vbw;
    #pragma unroll
    for (int p = 0; p < 4; ++p) {
      int it = p * 256 + wid * 64;
      glds16(ks + (size_t)(it + lane) * 8, &lds_k[0][it * 8]);
      glds16(vs + (size_t)(it + lane) * 8, &lds_v[0][it * 8]);
    }
  }
  __syncthreads();

  for (int t = 0; t < nt; ++t) {
    const int cur = t & 1;
    if (t + 1 < nt) {   // prefetch next tile (uniform branch)
      const unsigned short* ks = kb  + (size_t)(t + 1) * 8192;
      const unsigned short* vs = vbw + (size_t)(t + 1) * 8192;
      #pragma unroll
      for (int p = 0; p < 4; ++p) {
        int it = p * 256 + wid * 64;
        glds16(ks + (size_t)(it + lane) * 8, &lds_k[cur ^ 1][it * 8]);
        glds16(vs + (size_t)(it + lane) * 8, &lds_v[cur ^ 1][it * 8]);
      }
    }

    // ---- S = Q K^T (2 col-frags x 8 k-chunks) ----
    f32x4 s[2];
    #pragma unroll
    for (int kc = 0; kc < 2; ++kc) {
      f32x4 acc = (f32x4){0.f, 0.f, 0.f, 0.f};
      int krow = kc * 16 + l15;
      int sw = (krow & 7) << 3;
      #pragma unroll
      for (int dk = 0; dk < 8; ++dk) {
        int off = krow * 256 + ((dk * 32 + lg * 8) ^ sw);
        s16x8 kf = *(const s16x8*)(&lds_k[cur][off]);
        acc = __builtin_amdgcn_mfma_f32_16x16x32_bf16(
            __builtin_bit_cast(bf16x8_t, qf[dk]),
            __builtin_bit_cast(bf16x8_t, kf), acc, 0, 0, 0);
      }
      s[kc] = acc;
    }

    // ---- scale + key mask ----
    #pragma unroll
    for (int kc = 0; kc < 2; ++kc) {
      int gk = t * 32 + kc * 16 + l15;
      #pragma unroll
      for (int j = 0; j < 4; ++j) {
        float v = s[kc][j] * 0.0625f;
        s[kc][j] = (gk < n_k) ? v : -INFINITY;
      }
    }

    // ---- online softmax with defer-max (T13, THR=8) ----
    float pm[4];
    #pragma unroll
    for (int j = 0; j < 4; ++j) pm[j] = fmaxf(s[0][j], s[1][j]);
    #pragma unroll
    for (int off = 1; off < 16; off <<= 1) {
      #pragma unroll
      for (int j = 0; j < 4; ++j)
        pm[j] = fmaxf(pm[j], __shfl_xor(pm[j], off, 64));
    }
    int need = 0;
    #pragma unroll
    for (int j = 0; j < 4; ++j) need |= (pm[j] > m[j] + 8.0f) ? 1 : 0;
    if (__any(need)) {
      #pragma unroll
      for (int j = 0; j < 4; ++j) {
        float mn = fmaxf(m[j], pm[j]);
        float sc = __expf(m[j] - mn);   // first tile: exp(-inf)=0
        m[j] = mn;
        lsum[j] *= sc;
        #pragma unroll
        for (int c = 0; c < 16; ++c) o[c][j] *= sc;
      }
    }

    float psum[4] = {0.f, 0.f, 0.f, 0.f};
    #pragma unroll
    for (int kc = 0; kc < 2; ++kc) {
      #pragma unroll
      for (int j = 0; j < 4; ++j) {
        float p = __expf(s[kc][j] - m[j]);   // masked -> 0; bounded by e^8
        psum[j] += p;
        int r = lg * 4 + j;
        int col = kc * 16 + l15;
        int ke = col ^ (((r >> 1) & 3) << 3);
        lds_p[wid][r * 32 + ke] = f2bf(p);
      }
    }
    #pragma unroll
    for (int off = 1; off < 16; off <<= 1) {
      #pragma unroll
      for (int j = 0; j < 4; ++j)
        psum[j] += __shfl_xor(psum[j], off, 64);
    }
    #pragma unroll
    for (int j = 0; j < 4; ++j) lsum[j] += psum[j];

    // ---- P fragment (same-wave LDS round-trip) ----
    s16x8 pa = *(const s16x8*)(&lds_p[wid][l15 * 32 + ((lg ^ ((l15 >> 1) & 3)) << 3)]);

    // ---- O += P V ----
    #pragma unroll
    for (int c = 0; c < 16; ++c) {
      int dv = c * 16 + l15;
      int off = dv * 32 + ((lg ^ ((dv >> 1) & 3)) << 3);
      s16x8 vf = *(const s16x8*)(&lds_v[cur][off]);
      o[c] = __builtin_amdgcn_mfma_f32_16x16x32_bf16(
          __builtin_bit_cast(bf16x8_t, pa),
          __builtin_bit_cast(bf16x8_t, vf), o[c], 0, 0, 0);
    }

    __syncthreads();   // drains vmcnt (prefetch landed) + all reads of cur done
  }

  // ---- epilogue ----
  float inv[4];
  #pragma unroll
  for (int j = 0; j < 4; ++j) inv[j] = 1.0f / lsum[j];
  float* ob = O + ((size_t)b * LQ_ + qbase) * DV_;
  #pragma unroll
  for (int c = 0; c < 16; ++c) {
    #pragma unroll
    for (int j = 0; j < 4; ++j) {
      int r = lg * 4 + j;
      ob[(size_t)r * DV_ + c * 16 + l15] = o[c][j] * inv[j];
    }
  }
}

// ---------- fallback (round-1 kernel, used if ws too small) ----------
__global__ __launch_bounds__(256) void attn_fwd(
    const float* __restrict__ Q, const float* __restrict__ K,
    const float* __restrict__ V, const int* __restrict__ VL,
    float* __restrict__ O) {
  __shared__ __align__(16) unsigned short lds_k[64 * D_];
  __shared__ __align__(16) unsigned short lds_v[DV_ * 64];
  __shared__ __align__(16) unsigned short lds_p[NW][16 * 64];

  const int tid  = threadIdx.x;
  const int wid  = tid >> 6;
  const int lane = tid & 63;
  const int l15  = lane & 15;
  const int lg   = lane >> 4;
  const int bid = blockIdx.x;
  const int b   = bid >> 5;
  const int qt  = bid & 31;

  int n_k = (VL[1] == 0) ? VL[2 * b] : VL[b];
  if (n_k < 1) n_k = 1;
  if (n_k > LK_) n_k = LK_;

  const int qbase = qt * QB + wid * 16;
  s16x8 qf[8];
  {
    const float* qp = Q + ((size_t)b * LQ_ + qbase + l15) * D_ + lg * 8;
    #pragma unroll
    for (int dk = 0; dk < 8; ++dk) {
      float4 a = *(const float4*)(qp + dk * 32);
      float4 c = *(const float4*)(qp + dk * 32 + 4);
      qf[dk] = pack8(a, c);
    }
  }
  f32x4 o[16];
  #pragma unroll
  for (int c = 0; c < 16; ++c) o[c] = (f32x4){0.f, 0.f, 0.f, 0.f};
  float m[4]    = {-INFINITY, -INFINITY, -INFINITY, -INFINITY};
  float lsum[4] = {0.f, 0.f, 0.f, 0.f};
  const float* kb = K + (size_t)b * LK_ * D_;
  const float* vb = V + (size_t)b * LK_ * DV_;
  const int nt = (n_k + 63) / 64;

  for (int kt = 0; kt < nt; ++kt) {
    __syncthreads();
    {
      const float* src = kb + (size_t)kt * 64 * D_;
      #pragma unroll
      for (int p = 0; p < 8; ++p) {
        int e = (p * 256 + tid) * 8;
        int r = e >> 8;
        int d = e & 255;
        float4 a = *(const float4*)(src + e);
        float4 c = *(const float4*)(src + e + 4);
        int off = r * 256 + (d ^ ((r & 7) << 3));
        *(s16x8*)(&lds_k[off]) = pack8(a, c);
      }
    }
    {
      const float* src = vb + (size_t)kt * 64 * DV_;
      #pragma unroll
      for (int p = 0; p < 2; ++p) {
        int item = p * 256 + tid;
        int k0  = (item >> 5) * 4;
        int dv0 = (item & 31) * 8;
        float va[4][8];
        #pragma unroll
        for (int r = 0; r < 4; ++r) {
          float4 x = *(const float4*)(src + (k0 + r) * DV_ + dv0);
          float4 y = *(const float4*)(src + (k0 + r) * DV_ + dv0 + 4);
          va[r][0]=x.x; va[r][1]=x.y; va[r][2]=x.z; va[r][3]=x.w;
          va[r][4]=y.x; va[r][5]=y.y; va[r][6]=y.z; va[r][7]=y.w;
        }
        #pragma unroll
        for (int i = 0; i < 8; ++i) {
          int dv = dv0 + i;
          s16x4 w;
          w[0]=(short)f2bf(va[0][i]); w[1]=(short)f2bf(va[1][i]);
          w[2]=(short)f2bf(va[2][i]); w[3]=(short)f2bf(va[3][i]);
          int off = dv * 64 + (k0 ^ ((dv & 7) << 3));
          *(s16x4*)(&lds_v[off]) = w;
        }
      }
    }
    __syncthreads();

    f32x4 s[4];
    #pragma unroll
    for (int kc = 0; kc < 4; ++kc) {
      f32x4 acc = (f32x4){0.f, 0.f, 0.f, 0.f};
      int krow = kc * 16 + l15;
      int sw = (krow & 7) << 3;
      #pragma unroll
      for (int dk = 0; dk < 8; ++dk) {
        int off = krow * 256 + ((dk * 32 + lg * 8) ^ sw);
        s16x8 kf = *(const s16x8*)(&lds_k[off]);
        acc = __builtin_amdgcn_mfma_f32_16x16x32_bf16(
            __builtin_bit_cast(bf16x8_t, qf[dk]),
            __builtin_bit_cast(bf16x8_t, kf), acc, 0, 0, 0);
      }
      s[kc] = acc;
    }
    #pragma unroll
    for (int kc = 0; kc < 4; ++kc) {
      int gk = kt * 64 + kc * 16 + l15;
      #pragma unroll
      for (int j = 0; j < 4; ++j) {
        float v = s[kc][j] * 0.0625f;
        s[kc][j] = (gk < n_k) ? v : -INFINITY;
      }
    }
    float pm[4];
    #pragma unroll
    for (int j = 0; j < 4; ++j)
      pm[j] = fmaxf(fmaxf(s[0][j], s[1][j]), fmaxf(s[2][j], s[3][j]));
    #pragma unroll
    for (int off = 1; off < 16; off <<= 1) {
      #pragma unroll
      for (int j = 0; j < 4; ++j)
        pm[j] = fmaxf(pm[j], __shfl_xor(pm[j], off, 64));
    }
    float sc[4];
    #pragma unroll
    for (int j = 0; j < 4; ++j) {
      float mn = fmaxf(m[j], pm[j]);
      sc[j] = __expf(m[j] - mn);
      m[j] = mn;
    }
    float psum[4] = {0.f, 0.f, 0.f, 0.f};
    #pragma unroll
    for (int kc = 0; kc < 4; ++kc) {
      #pragma unroll
      for (int j = 0; j < 4; ++j) {
        float p = __expf(s[kc][j] - m[j]);
        psum[j] += p;
        int r = lg * 4 + j;
        int col = kc * 16 + l15;
        lds_p[wid][r * 64 + (col ^ ((r & 7) << 3))] = f2bf(p);
      }
    }
    #pragma unroll
    for (int off = 1; off < 16; off <<= 1) {
      #pragma unroll
      for (int j = 0; j < 4; ++j)
        psum[j] += __shfl_xor(psum[j], off, 64);
    }
    #pragma unroll
    for (int j = 0; j < 4; ++j) lsum[j] = lsum[j] * sc[j] + psum[j];
    #pragma unroll
    for (int c = 0; c < 16; ++c) {
      #pragma unroll
      for (int j = 0; j < 4; ++j) o[c][j] *= sc[j];
    }
    s16x8 pa[2];
    #pragma unroll
    for (int kk = 0; kk < 2; ++kk) {
      int r = l15;
      int k = kk * 32 + lg * 8;
      pa[kk] = *(const s16x8*)(&lds_p[wid][r * 64 + (k ^ ((r & 7) << 3))]);
    }
    #pragma unroll
    for (int c = 0; c < 16; ++c) {
      #pragma unroll
      for (int kk = 0; kk < 2; ++kk) {
        int dv = c * 16 + l15;
        int k = kk * 32 + lg * 8;
        s16x8 vf = *(const s16x8*)(&lds_v[dv * 64 + (k ^ ((dv & 7) << 3))]);
        o[c] = __builtin_amdgcn_mfma_f32_16x16x32_bf16(
            __builtin_bit_cast(bf16x8_t, pa[kk]),
            __builtin_bit_cast(bf16x8_t, vf), o[c], 0, 0, 0);
      }
    }
  }
  float inv[4];
  #pragma unroll
  for (int j = 0; j < 4; ++j) inv[j] = 1.0f / lsum[j];
  float* ob = O + ((size_t)b * LQ_ + qbase) * DV_;
  #pragma unroll
  for (int c = 0; c < 16; ++c) {
    #pragma unroll
    for (int j = 0; j < 4; ++j) {
      int r = lg * 4 + j;
      ob[(size_t)r * DV_ + c * 16 + l15] = o[c][j] * inv[j];
    }
  }
}

extern "C" void kernel_launch(void* const* d_in, const int* in_sizes, int n_in,
                              void* d_out, int out_size, void* d_ws, size_t ws_size,
                              hipStream_t stream) {
  const float* Q  = (const float*)d_in[0];
  const float* K  = (const float*)d_in[1];
  const float* V  = (const float*)d_in[2];
  const int*   VL = (const int*)d_in[3];
  float* O = (float*)d_out;

  const size_t kv_elems = (size_t)B_ * LK_ * D_;           // 8,388,608
  const size_t need = kv_elems * 2 * sizeof(unsigned short); // 32 MB
  if (ws_size >= need) {
    unsigned short* wsK = (unsigned short*)d_ws;
    unsigned short* wsV = wsK + kv_elems;
    prep_k<<<dim3(4096), dim3(256), 0, stream>>>(K, wsK);
    prep_v<<<dim3(1024), dim3(256), 0, stream>>>(V, wsV);
    attn_fwd2<<<dim3(512), dim3(256), 0, stream>>>(Q, wsK, wsV, VL, O);
  } else {
    attn_fwd<<<dim3(512), dim3(256), 0, stream>>>(Q, K, V, VL, O);
  }
}

// Round 3
// 135.662 us; speedup vs baseline: 2.6699x; 1.2387x over previous
//
#include <hip/hip_runtime.h>
#include <hip/hip_bf16.h>

#define B_   16
#define LQ_  2048
#define LK_  2048
#define D_   256
#define DV_  256
#define MINF -1.0e30f

typedef __bf16 bf16x8_t __attribute__((ext_vector_type(8)));
typedef short  s16x8    __attribute__((ext_vector_type(8)));
typedef short  s16x4    __attribute__((ext_vector_type(4)));
typedef float  f32x4    __attribute__((ext_vector_type(4)));

__device__ __forceinline__ unsigned short f2bf(float f) {
  unsigned int u = __builtin_bit_cast(unsigned int, f);
  u += 0x7fffu + ((u >> 16) & 1u);   // RNE (finite inputs)
  return (unsigned short)(u >> 16);
}

__device__ __forceinline__ s16x8 pack8(float4 a, float4 b) {
  s16x8 r;
  r[0] = (short)f2bf(a.x); r[1] = (short)f2bf(a.y);
  r[2] = (short)f2bf(a.z); r[3] = (short)f2bf(a.w);
  r[4] = (short)f2bf(b.x); r[5] = (short)f2bf(b.y);
  r[6] = (short)f2bf(b.z); r[7] = (short)f2bf(b.w);
  return r;
}

__device__ __forceinline__ void glds16(const unsigned short* g, unsigned short* l) {
  __builtin_amdgcn_global_load_lds(
      (const __attribute__((address_space(1))) unsigned int*)g,
      (__attribute__((address_space(3))) unsigned int*)l, 16, 0, 0);
}

// ---------- prepass: K -> bf16, row-major, chunk-XOR pre-swizzled ----------
__global__ __launch_bounds__(256) void prep_k(const float* __restrict__ K,
                                              unsigned short* __restrict__ wsK) {
  int gid = blockIdx.x * 256 + threadIdx.x;
  int gr = gid >> 5;
  int c  = gid & 31;
  const float* src = K + ((size_t)gr << 8) + c * 8;
  float4 a = *(const float4*)(src);
  float4 b = *(const float4*)(src + 4);
  *(s16x8*)(wsK + ((size_t)gr << 8) + ((c ^ (gr & 7)) << 3)) = pack8(a, b);
}

// ---------- prepass: V -> bf16, transposed per 64-key tile, 8-chunk-XOR ----
// ws image == LDS image: ws[dv*64 + ((ch ^ (dv&7))<<3) + e] = V[tile*64 + ch*8+e][dv]
__global__ __launch_bounds__(256) void prep_v(const float* __restrict__ V,
                                              unsigned short* __restrict__ wsV) {
  __shared__ unsigned short t[256 * 72];          // [dv][64k + 8 pad]
  const int tid = threadIdx.x;
  const float* src = V + (size_t)blockIdx.x * 64 * 256;
  #pragma unroll
  for (int i = 0; i < 16; ++i) {
    int idx = i * 256 + tid;
    int k   = idx >> 6;
    int dv0 = (idx & 63) * 4;
    float4 x = *(const float4*)(src + k * 256 + dv0);
    t[(dv0 + 0) * 72 + k] = f2bf(x.x);
    t[(dv0 + 1) * 72 + k] = f2bf(x.y);
    t[(dv0 + 2) * 72 + k] = f2bf(x.z);
    t[(dv0 + 3) * 72 + k] = f2bf(x.w);
  }
  __syncthreads();
  unsigned short* dst = wsV + (size_t)blockIdx.x * 16384;
  #pragma unroll
  for (int i = 0; i < 8; ++i) {
    int idx = i * 256 + tid;
    int dv = idx >> 3;
    int ch = idx & 7;
    s16x8 v = *(const s16x8*)(&t[dv * 72 + ch * 8]);
    *(s16x8*)(dst + dv * 64 + ((ch ^ (dv & 7)) << 3)) = v;
  }
}

// ---------- main v3: 8 waves, QB=64, KB=64, k-split + end merge ----------
__global__ __launch_bounds__(512) void attn_fwd3(
    const float* __restrict__ Q, const unsigned short* __restrict__ wsK,
    const unsigned short* __restrict__ wsV, const int* __restrict__ VL,
    float* __restrict__ O) {
  // [0],[1] = K dbuf (64x256 bf16 each); [2],[3] = V dbuf (256x64 bf16 each)
  __shared__ __align__(16) unsigned short lds_s[4][16384];   // 128 KB

  const int tid  = threadIdx.x;
  const int wid  = tid >> 6;
  const int lane = tid & 63;
  const int l15  = lane & 15;
  const int lg   = lane >> 4;
  const int rg   = wid & 3;        // row quadrant (16 q-rows)
  const int kh   = wid >> 2;       // k-half of each 64-key tile

  const int bid = blockIdx.x;
  const int b   = bid >> 5;
  const int qt  = bid & 31;

  int n_k = (VL[1] == 0) ? VL[2 * b] : VL[b];
  if (n_k < 1) n_k = 1;
  if (n_k > LK_) n_k = LK_;
  const int nt = (n_k + 63) >> 6;

  const int qbase = qt * 64 + rg * 16;

  // Q fragment (B-operand): lane holds Q[qbase+l15][dk*32 + lg*8 .. +8]
  s16x8 qf[8];
  {
    const float* qp = Q + ((size_t)b * LQ_ + qbase + l15) * D_ + lg * 8;
    #pragma unroll
    for (int dk = 0; dk < 8; ++dk) {
      float4 a = *(const float4*)(qp + dk * 32);
      float4 c = *(const float4*)(qp + dk * 32 + 4);
      qf[dk] = pack8(a, c);
    }
  }

  f32x4 o[16];
  #pragma unroll
  for (int c = 0; c < 16; ++c) o[c] = (f32x4){0.f, 0.f, 0.f, 0.f};
  float m = MINF, l = 0.f;

  const unsigned short* kbw = wsK + (size_t)b * LK_ * D_;
  const unsigned short* vbw = wsV + (size_t)b * LK_ * DV_;

#define STAGE(buf, t) do {                                                   \
    const unsigned short* ks_ = kbw + (size_t)(t) * 16384;                   \
    const unsigned short* vs_ = vbw + (size_t)(t) * 16384;                   \
    _Pragma("unroll")                                                        \
    for (int p = 0; p < 4; ++p) {                                            \
      int cu = p * 512 + wid * 64;                                           \
      glds16(ks_ + (size_t)(cu + lane) * 8, &lds_s[(buf)][cu * 8]);          \
      glds16(vs_ + (size_t)(cu + lane) * 8, &lds_s[2 + (buf)][cu * 8]);      \
    }                                                                        \
  } while (0)

  STAGE(0, 0);
  __syncthreads();

  for (int t = 0; t < nt; ++t) {
    const int cur = t & 1;
    if (t + 1 < nt) STAGE(cur ^ 1, t + 1);

    // ---- S^T = K Q^T over this wave's 32-key window (2 kc x 4+4 chains) ----
    const unsigned short* kl = &lds_s[cur][0];
    f32x4 s[2];
    __builtin_amdgcn_s_setprio(1);
    #pragma unroll
    for (int kc = 0; kc < 2; ++kc) {
      int krow = kh * 32 + kc * 16 + l15;
      int sw = (krow & 7) << 3;
      const unsigned short* base = kl + krow * 256;
      f32x4 a0 = (f32x4){0.f, 0.f, 0.f, 0.f};
      f32x4 a1 = (f32x4){0.f, 0.f, 0.f, 0.f};
      #pragma unroll
      for (int dk = 0; dk < 4; ++dk) {
        s16x8 k0 = *(const s16x8*)(base + ((dk * 64 + lg * 8) ^ sw));
        s16x8 k1 = *(const s16x8*)(base + ((dk * 64 + 32 + lg * 8) ^ sw));
        a0 = __builtin_amdgcn_mfma_f32_16x16x32_bf16(
            __builtin_bit_cast(bf16x8_t, k0),
            __builtin_bit_cast(bf16x8_t, qf[2 * dk]), a0, 0, 0, 0);
        a1 = __builtin_amdgcn_mfma_f32_16x16x32_bf16(
            __builtin_bit_cast(bf16x8_t, k1),
            __builtin_bit_cast(bf16x8_t, qf[2 * dk + 1]), a1, 0, 0, 0);
      }
      s[kc] = a0 + a1;
    }
    __builtin_amdgcn_s_setprio(0);

    // ---- scale + key mask (rows = keys) ----
    #pragma unroll
    for (int kc = 0; kc < 2; ++kc) {
      int gk = t * 64 + kh * 32 + kc * 16 + lg * 4;
      #pragma unroll
      for (int j = 0; j < 4; ++j)
        s[kc][j] = (gk + j < n_k) ? s[kc][j] * 0.0625f : MINF;
    }

    // ---- online softmax, lane-local q = l15, defer-max THR=8 ----
    float pm = s[0][0];
    pm = fmaxf(pm, s[0][1]); pm = fmaxf(pm, s[0][2]); pm = fmaxf(pm, s[0][3]);
    pm = fmaxf(pm, s[1][0]); pm = fmaxf(pm, s[1][1]);
    pm = fmaxf(pm, s[1][2]); pm = fmaxf(pm, s[1][3]);
    pm = fmaxf(pm, __shfl_xor(pm, 16, 64));
    pm = fmaxf(pm, __shfl_xor(pm, 32, 64));
    if (__any(pm > m + 8.0f)) {
      float mn = fmaxf(m, pm);
      float sc = __expf(m - mn);
      m = mn; l *= sc;
      #pragma unroll
      for (int c = 0; c < 16; ++c) o[c] = o[c] * sc;
    }
    float p0[4], p1[4];
    #pragma unroll
    for (int j = 0; j < 4; ++j) {
      p0[j] = __expf(s[0][j] - m);
      p1[j] = __expf(s[1][j] - m);
    }
    float ps = ((p0[0] + p0[1]) + (p0[2] + p0[3]))
             + ((p1[0] + p1[1]) + (p1[2] + p1[3]));
    ps += __shfl_xor(ps, 16, 64);
    ps += __shfl_xor(ps, 32, 64);
    l += ps;

    // ---- in-register P transpose -> B-frag pb (16 shfl + select) ----
    float pv8[8];
    int sl0 = l15 + ((lg & 1) ? 32 : 0);
    #pragma unroll
    for (int h = 0; h < 2; ++h) {
      int sl = sl0 + h * 16;
      #pragma unroll
      for (int j = 0; j < 4; ++j) {
        float a  = __shfl(p0[j], sl, 64);
        float bb = __shfl(p1[j], sl, 64);
        pv8[h * 4 + j] = (lg >= 2) ? bb : a;
      }
    }
    s16x8 pb;
    #pragma unroll
    for (int e = 0; e < 8; ++e) pb[e] = (short)f2bf(pv8[e]);

    // ---- O^T += V^T P^T over this wave's 32 keys ----
    const unsigned short* vl_ = &lds_s[2 + cur][0];
    __builtin_amdgcn_s_setprio(1);
    #pragma unroll
    for (int c = 0; c < 16; ++c) {
      int dv = c * 16 + l15;
      int off = dv * 64 + (((kh * 4 + lg) ^ (dv & 7)) << 3);
      s16x8 vf = *(const s16x8*)(vl_ + off);
      o[c] = __builtin_amdgcn_mfma_f32_16x16x32_bf16(
          __builtin_bit_cast(bf16x8_t, vf),
          __builtin_bit_cast(bf16x8_t, pb), o[c], 0, 0, 0);
    }
    __builtin_amdgcn_s_setprio(0);

    __syncthreads();   // buffer reuse + prefetch drain
  }

  // ---- merge k-halves: wave pair (rg, rg+4) combine, then write ----
  float* mrg = (float*)&lds_s[0][0];
  float* mo  = mrg + (wid & 3) * 4160;   // [q=16][stride 257] + m/l at 4112/4128
  if (wid >= 4) {
    #pragma unroll
    for (int c = 0; c < 16; ++c)
      #pragma unroll
      for (int j = 0; j < 4; ++j)
        mo[l15 * 257 + c * 16 + lg * 4 + j] = o[c][j];
    mo[4112 + l15] = m;    // 4 lg lanes write same value (benign)
    mo[4128 + l15] = l;
  }
  __syncthreads();
  if (wid < 4) {
    float mb = mo[4112 + l15];
    float lb = mo[4128 + l15];
    float M  = fmaxf(m, mb);
    float sa = __expf(m - M), sb = __expf(mb - M);
    float invL = 1.0f / (sa * l + sb * lb);
    float* ob = O + ((size_t)b * LQ_ + qbase + l15) * DV_;
    #pragma unroll
    for (int c = 0; c < 16; ++c) {
      int dvb = c * 16 + lg * 4;
      const float* mr = mo + l15 * 257 + dvb;
      float4 r;
      r.x = (sa * o[c][0] + sb * mr[0]) * invL;
      r.y = (sa * o[c][1] + sb * mr[1]) * invL;
      r.z = (sa * o[c][2] + sb * mr[2]) * invL;
      r.w = (sa * o[c][3] + sb * mr[3]) * invL;
      *(float4*)(ob + dvb) = r;
    }
  }
#undef STAGE
}

// ---------- fallback (round-1 kernel, used if ws too small) ----------
__global__ __launch_bounds__(256) void attn_fwd(
    const float* __restrict__ Q, const float* __restrict__ K,
    const float* __restrict__ V, const int* __restrict__ VL,
    float* __restrict__ O) {
  __shared__ __align__(16) unsigned short lds_k[64 * D_];
  __shared__ __align__(16) unsigned short lds_v[DV_ * 64];
  __shared__ __align__(16) unsigned short lds_p[4][16 * 64];

  const int tid  = threadIdx.x;
  const int wid  = tid >> 6;
  const int lane = tid & 63;
  const int l15  = lane & 15;
  const int lg   = lane >> 4;
  const int bid = blockIdx.x;
  const int b   = bid >> 5;
  const int qt  = bid & 31;

  int n_k = (VL[1] == 0) ? VL[2 * b] : VL[b];
  if (n_k < 1) n_k = 1;
  if (n_k > LK_) n_k = LK_;

  const int qbase = qt * 64 + wid * 16;
  s16x8 qf[8];
  {
    const float* qp = Q + ((size_t)b * LQ_ + qbase + l15) * D_ + lg * 8;
    #pragma unroll
    for (int dk = 0; dk < 8; ++dk) {
      float4 a = *(const float4*)(qp + dk * 32);
      float4 c = *(const float4*)(qp + dk * 32 + 4);
      qf[dk] = pack8(a, c);
    }
  }
  f32x4 o[16];
  #pragma unroll
  for (int c = 0; c < 16; ++c) o[c] = (f32x4){0.f, 0.f, 0.f, 0.f};
  float m[4]    = {-INFINITY, -INFINITY, -INFINITY, -INFINITY};
  float lsum[4] = {0.f, 0.f, 0.f, 0.f};
  const float* kb = K + (size_t)b * LK_ * D_;
  const float* vb = V + (size_t)b * LK_ * DV_;
  const int nt = (n_k + 63) / 64;

  for (int kt = 0; kt < nt; ++kt) {
    __syncthreads();
    {
      const float* src = kb + (size_t)kt * 64 * D_;
      #pragma unroll
      for (int p = 0; p < 8; ++p) {
        int e = (p * 256 + tid) * 8;
        int r = e >> 8;
        int d = e & 255;
        float4 a = *(const float4*)(src + e);
        float4 c = *(const float4*)(src + e + 4);
        *(s16x8*)(&lds_k[r * 256 + (d ^ ((r & 7) << 3))]) = pack8(a, c);
      }
    }
    {
      const float* src = vb + (size_t)kt * 64 * DV_;
      #pragma unroll
      for (int p = 0; p < 2; ++p) {
        int item = p * 256 + tid;
        int k0  = (item >> 5) * 4;
        int dv0 = (item & 31) * 8;
        float va[4][8];
        #pragma unroll
        for (int r = 0; r < 4; ++r) {
          float4 x = *(const float4*)(src + (k0 + r) * DV_ + dv0);
          float4 y = *(const float4*)(src + (k0 + r) * DV_ + dv0 + 4);
          va[r][0]=x.x; va[r][1]=x.y; va[r][2]=x.z; va[r][3]=x.w;
          va[r][4]=y.x; va[r][5]=y.y; va[r][6]=y.z; va[r][7]=y.w;
        }
        #pragma unroll
        for (int i = 0; i < 8; ++i) {
          int dv = dv0 + i;
          s16x4 w;
          w[0]=(short)f2bf(va[0][i]); w[1]=(short)f2bf(va[1][i]);
          w[2]=(short)f2bf(va[2][i]); w[3]=(short)f2bf(va[3][i]);
          *(s16x4*)(&lds_v[dv * 64 + (k0 ^ ((dv & 7) << 3))]) = w;
        }
      }
    }
    __syncthreads();

    f32x4 s[4];
    #pragma unroll
    for (int kc = 0; kc < 4; ++kc) {
      f32x4 acc = (f32x4){0.f, 0.f, 0.f, 0.f};
      int krow = kc * 16 + l15;
      int sw = (krow & 7) << 3;
      #pragma unroll
      for (int dk = 0; dk < 8; ++dk) {
        s16x8 kf = *(const s16x8*)(&lds_k[krow * 256 + ((dk * 32 + lg * 8) ^ sw)]);
        acc = __builtin_amdgcn_mfma_f32_16x16x32_bf16(
            __builtin_bit_cast(bf16x8_t, qf[dk]),
            __builtin_bit_cast(bf16x8_t, kf), acc, 0, 0, 0);
      }
      s[kc] = acc;
    }
    #pragma unroll
    for (int kc = 0; kc < 4; ++kc) {
      int gk = kt * 64 + kc * 16 + l15;
      #pragma unroll
      for (int j = 0; j < 4; ++j) {
        float v = s[kc][j] * 0.0625f;
        s[kc][j] = (gk < n_k) ? v : -INFINITY;
      }
    }
    float pm[4];
    #pragma unroll
    for (int j = 0; j < 4; ++j)
      pm[j] = fmaxf(fmaxf(s[0][j], s[1][j]), fmaxf(s[2][j], s[3][j]));
    #pragma unroll
    for (int off = 1; off < 16; off <<= 1) {
      #pragma unroll
      for (int j = 0; j < 4; ++j)
        pm[j] = fmaxf(pm[j], __shfl_xor(pm[j], off, 64));
    }
    float sc[4];
    #pragma unroll
    for (int j = 0; j < 4; ++j) {
      float mn = fmaxf(m[j], pm[j]);
      sc[j] = __expf(m[j] - mn);
      m[j] = mn;
    }
    float psum[4] = {0.f, 0.f, 0.f, 0.f};
    #pragma unroll
    for (int kc = 0; kc < 4; ++kc) {
      #pragma unroll
      for (int j = 0; j < 4; ++j) {
        float p = __expf(s[kc][j] - m[j]);
        psum[j] += p;
        int r = lg * 4 + j;
        lds_p[wid][r * 64 + ((kc * 16 + l15) ^ ((r & 7) << 3))] = f2bf(p);
      }
    }
    #pragma unroll
    for (int off = 1; off < 16; off <<= 1) {
      #pragma unroll
      for (int j = 0; j < 4; ++j)
        psum[j] += __shfl_xor(psum[j], off, 64);
    }
    #pragma unroll
    for (int j = 0; j < 4; ++j) lsum[j] = lsum[j] * sc[j] + psum[j];
    #pragma unroll
    for (int c = 0; c < 16; ++c) {
      #pragma unroll
      for (int j = 0; j < 4; ++j) o[c][j] *= sc[j];
    }
    s16x8 pa[2];
    #pragma unroll
    for (int kk = 0; kk < 2; ++kk)
      pa[kk] = *(const s16x8*)(&lds_p[wid][l15 * 64 + ((kk * 32 + lg * 8) ^ ((l15 & 7) << 3))]);
    #pragma unroll
    for (int c = 0; c < 16; ++c) {
      #pragma unroll
      for (int kk = 0; kk < 2; ++kk) {
        int dv = c * 16 + l15;
        s16x8 vf = *(const s16x8*)(&lds_v[dv * 64 + ((kk * 32 + lg * 8) ^ ((dv & 7) << 3))]);
        o[c] = __builtin_amdgcn_mfma_f32_16x16x32_bf16(
            __builtin_bit_cast(bf16x8_t, pa[kk]),
            __builtin_bit_cast(bf16x8_t, vf), o[c], 0, 0, 0);
      }
    }
  }
  float inv[4];
  #pragma unroll
  for (int j = 0; j < 4; ++j) inv[j] = 1.0f / lsum[j];
  float* ob = O + ((size_t)b * LQ_ + qbase) * DV_;
  #pragma unroll
  for (int c = 0; c < 16; ++c) {
    #pragma unroll
    for (int j = 0; j < 4; ++j) {
      int r = lg * 4 + j;
      ob[(size_t)r * DV_ + c * 16 + l15] = o[c][j] * inv[j];
    }
  }
}

extern "C" void kernel_launch(void* const* d_in, const int* in_sizes, int n_in,
                              void* d_out, int out_size, void* d_ws, size_t ws_size,
                              hipStream_t stream) {
  const float* Q  = (const float*)d_in[0];
  const float* K  = (const float*)d_in[1];
  const float* V  = (const float*)d_in[2];
  const int*   VL = (const int*)d_in[3];
  float* O = (float*)d_out;

  const size_t kv_elems = (size_t)B_ * LK_ * D_;
  const size_t need = kv_elems * 2 * sizeof(unsigned short);
  if (ws_size >= need) {
    unsigned short* wsK = (unsigned short*)d_ws;
    unsigned short* wsV = wsK + kv_elems;
    prep_k<<<dim3(4096), dim3(256), 0, stream>>>(K, wsK);
    prep_v<<<dim3(512), dim3(256), 0, stream>>>(V, wsV);
    attn_fwd3<<<dim3(512), dim3(512), 0, stream>>>(Q, wsK, wsV, VL, O);
  } else {
    attn_fwd<<<dim3(512), dim3(256), 0, stream>>>(Q, K, V, VL, O);
  }
}